// Round 4
// baseline (492.428 us; speedup 1.0000x reference)
//
#include <hip/hip_runtime.h>
#include <math.h>

#define NODES   131072
#define EDGES   1048576
#define FDIM    32
#define HDIM    128
#define NGRAPH  512

typedef __attribute__((ext_vector_type(8))) short short8v;
typedef __attribute__((ext_vector_type(4))) float float4v;

__device__ __forceinline__ unsigned short f2bf(float f) {
    union { float f; unsigned int u; } v; v.f = f;
    unsigned int u = v.u;
    unsigned int r = (u + 0x7fffu + ((u >> 16) & 1u)) >> 16;   // RNE
    return (unsigned short)r;
}
__device__ __forceinline__ float bf2f(unsigned short u) {
    union { unsigned int u; float f; } v; v.u = ((unsigned int)u) << 16; return v.f;
}

// ---------------------------------------------------------------- k1 | hist fused
// blocks [0,2048): h0b = bf16(X @ W_in); blocks [2048,6144): degree histogram
__global__ __launch_bounds__(256) void k1_hist(const float* __restrict__ x,
                                               const float* __restrict__ Win,
                                               unsigned short* __restrict__ h0b,
                                               const int* __restrict__ ei,
                                               int* __restrict__ count) {
    int b = blockIdx.x, t = threadIdx.x;
    if (b < 2048) {
        int col = t & (HDIM - 1);
        int group0 = (int)(((size_t)b * 256 + t) >> 7);
        const int stride = 4096;
        for (int n = group0; n < NODES; n += stride) {
            const float* xr = x + (size_t)n * FDIM;
            float s = 0.f;
#pragma unroll
            for (int f = 0; f < FDIM; ++f)
                s = fmaf(xr[f], Win[f * HDIM + col], s);
            h0b[(size_t)n * HDIM + col] = f2bf(s);
        }
    } else {
        int e = (b - 2048) * 256 + t;
        atomicAdd(&count[ei[EDGES + e]], 1);
    }
}

// ---------------------------------------------------------------- scans
__global__ __launch_bounds__(256) void kh_scanA(const int* __restrict__ count,
                                                int* __restrict__ offs,
                                                int* __restrict__ blockSums) {
    int b = blockIdx.x, t = threadIdx.x;
    int base = b * 512 + 2 * t;
    int a0 = count[base], a1 = count[base + 1];
    int pair = a0 + a1;
    __shared__ int sh[256];
    sh[t] = pair;
    __syncthreads();
    for (int off = 1; off < 256; off <<= 1) {
        int v = (t >= off) ? sh[t - off] : 0;
        __syncthreads();
        sh[t] += v;
        __syncthreads();
    }
    int excl = sh[t] - pair;
    offs[base] = excl;
    offs[base + 1] = excl + a0;
    if (t == 255) blockSums[b] = sh[255];
}

// scanC with scanB inlined (each block redundantly scans the 256 block sums)
__global__ __launch_bounds__(256) void kh_scanC(int* __restrict__ offs,
                                                int* __restrict__ cursor,
                                                const int* __restrict__ bsums) {
    int b = blockIdx.x, t = threadIdx.x;
    __shared__ int sh[256];
    sh[t] = bsums[t];
    __syncthreads();
    for (int off = 1; off < 256; off <<= 1) {
        int v = (t >= off) ? sh[t - off] : 0;
        __syncthreads();
        sh[t] += v;
        __syncthreads();
    }
    int add = (b > 0) ? sh[b - 1] : 0;
    int base = b * 512 + 2 * t;
    int o0 = offs[base] + add, o1 = offs[base + 1] + add;
    offs[base] = o0; offs[base + 1] = o1;
    cursor[base] = o0; cursor[base + 1] = o1;
}

__global__ __launch_bounds__(256) void kh_fill(const int* __restrict__ ei,
                                               const float* __restrict__ ew,
                                               int* __restrict__ cursor,
                                               int2* __restrict__ bucket, int E) {
    int e = blockIdx.x * blockDim.x + threadIdx.x;
    if (e >= E) return;
    int src = ei[e];
    int tgt = ei[E + e];
    float w = ew[e];
    int pos = atomicAdd(&cursor[tgt], 1);
    bucket[pos] = make_int2(src, __float_as_int(w));
}

// ---------------------------------------------------------------- prep: wfrag | cnt | gsum-zero
__global__ __launch_bounds__(256) void kprep(const float* __restrict__ Wmsg,
                                             unsigned short* __restrict__ wfrag,
                                             const int* __restrict__ batch,
                                             int* __restrict__ cnt,
                                             float* __restrict__ gsum) {
    int b = blockIdx.x, t = threadIdx.x;
    if (b < 8) {
        int flat = b * 256 + t;                 // 0..2047
        int l = flat & 63;
        int fragid = flat >> 6;                 // 0..31
        int c = fragid >> 2, kk = fragid & 3;
        int col = c * 16 + (l & 15);
        int k0 = kk * 32 + (l >> 4) * 8;
        short8v v;
#pragma unroll
        for (int j = 0; j < 8; ++j)
            v[j] = (short)f2bf(Wmsg[(k0 + j) * HDIM + col]);
        ((short8v*)wfrag)[flat] = v;
    } else if (b < 10) {
        int g = (b - 8) * 256 + t;
        if (g < NGRAPH) {
            int lo = 0, hi = NODES;
            while (lo < hi) { int m = (lo + hi) >> 1; if (batch[m] < g) lo = m + 1; else hi = m; }
            int start = lo;
            hi = NODES;
            while (lo < hi) { int m = (lo + hi) >> 1; if (batch[m] < g + 1) lo = m + 1; else hi = m; }
            cnt[g] = lo - start;
        }
    } else {
        float4* gz = (float4*)gsum;             // 512*128 floats = 16384 float4
        int idx = (b - 10) * 256 + t;
        for (int i = idx; i < 16384; i += 512) gz[i] = make_float4(0.f, 0.f, 0.f, 0.f);
    }
}

// ---------------------------------------------------------------- gather: msgb[n] = bf16( sum_in h0b[src]*w )
__global__ __launch_bounds__(256) void kg_gather(const unsigned short* __restrict__ h0b,
                                                 const int* __restrict__ offs,
                                                 const int* __restrict__ cursor,
                                                 const int2* __restrict__ bucket,
                                                 unsigned short* __restrict__ msgb, int N) {
    long long gid = blockIdx.x * (long long)blockDim.x + threadIdx.x;
    int n = (int)(gid >> 6);
    if (n >= N) return;
    int l = (int)(gid & 63);
    int beg = offs[n];
    int end = cursor[n];
    float ax = 0.f, ay = 0.f;
    int j = beg;
    for (; j + 4 <= end; j += 4) {
        int2 e0 = bucket[j], e1 = bucket[j + 1], e2 = bucket[j + 2], e3 = bucket[j + 3];
        unsigned int u0 = ((const unsigned int*)(h0b + (size_t)e0.x * HDIM))[l];
        unsigned int u1 = ((const unsigned int*)(h0b + (size_t)e1.x * HDIM))[l];
        unsigned int u2 = ((const unsigned int*)(h0b + (size_t)e2.x * HDIM))[l];
        unsigned int u3 = ((const unsigned int*)(h0b + (size_t)e3.x * HDIM))[l];
        float w0 = __int_as_float(e0.y), w1 = __int_as_float(e1.y);
        float w2 = __int_as_float(e2.y), w3 = __int_as_float(e3.y);
        ax = fmaf(__uint_as_float(u0 << 16), w0, ax); ay = fmaf(__uint_as_float(u0 & 0xFFFF0000u), w0, ay);
        ax = fmaf(__uint_as_float(u1 << 16), w1, ax); ay = fmaf(__uint_as_float(u1 & 0xFFFF0000u), w1, ay);
        ax = fmaf(__uint_as_float(u2 << 16), w2, ax); ay = fmaf(__uint_as_float(u2 & 0xFFFF0000u), w2, ay);
        ax = fmaf(__uint_as_float(u3 << 16), w3, ax); ay = fmaf(__uint_as_float(u3 & 0xFFFF0000u), w3, ay);
    }
    for (; j < end; ++j) {
        int2 e0 = bucket[j];
        unsigned int u0 = ((const unsigned int*)(h0b + (size_t)e0.x * HDIM))[l];
        float w0 = __int_as_float(e0.y);
        ax = fmaf(__uint_as_float(u0 << 16), w0, ax); ay = fmaf(__uint_as_float(u0 & 0xFFFF0000u), w0, ay);
    }
    ushort2 o; o.x = f2bf(ax); o.y = f2bf(ay);
    ((ushort2*)(msgb + (size_t)n * HDIM))[l] = o;
}

// ---------------------------------------------------------------- k3a: MFMA GEMM + relu + fused pool
// 128 nodes/block, 4 waves, 2 strips/wave. B fragments staged in LDS (32KB).
__global__ __launch_bounds__(256) void k3a_mfma_pool(const unsigned short* __restrict__ msgb,
                                                     const unsigned short* __restrict__ h0b,
                                                     const unsigned short* __restrict__ wfrag,
                                                     const int* __restrict__ batch,
                                                     float* __restrict__ gsum) {
    __shared__ __align__(16) unsigned short blds[32 * 64 * 8];  // 32KB
    __shared__ float pool[8][HDIM];                              // 4KB

    int t = threadIdx.x;
    int wid = t >> 6, l = t & 63;
    int base = blockIdx.x * 128;

    // cooperative stage of B fragments
    {
        const uint4* s = (const uint4*)wfrag;
        uint4* d = (uint4*)blds;
#pragma unroll
        for (int i = 0; i < 8; ++i) d[t + 256 * i] = s[t + 256 * i];
    }

    int bfirst = batch[base];
    int blast  = batch[base + 127];
    int span = blast - bfirst + 1;
    bool lds_pool = (span <= 8);
    if (lds_pool) {
        float* pf = (float*)pool;
        for (int i = t; i < 8 * HDIM; i += 256) pf[i] = 0.f;
    }
    __syncthreads();

    const short8v* Bl = (const short8v*)blds;
    int col = l & 15;
    int rsub = (l >> 4) * 4;

#pragma unroll
    for (int s = 0; s < 2; ++s) {
        int strip = base + wid * 32 + s * 16;
        const short8v* mrow = (const short8v*)(msgb + (size_t)(strip + col) * HDIM);
        short8v af[4];
#pragma unroll
        for (int kk = 0; kk < 4; ++kk)
            af[kk] = mrow[kk * 4 + (l >> 4)];

        float4v acc[8];
#pragma unroll
        for (int c = 0; c < 8; ++c) acc[c] = (float4v){0.f, 0.f, 0.f, 0.f};
#pragma unroll
        for (int kk = 0; kk < 4; ++kk)
#pragma unroll
            for (int c = 0; c < 8; ++c)
                acc[c] = __builtin_amdgcn_mfma_f32_16x16x32_bf16(af[kk], Bl[(c * 4 + kk) * 64 + l], acc[c], 0, 0, 0);

        int rbase = strip + rsub;   // C/D: col = lane&15, row = (lane>>4)*4 + reg
        if (lds_pool) {
#pragma unroll
            for (int r = 0; r < 4; ++r) {
                int row = rbase + r;
                int g = batch[row] - bfirst;
#pragma unroll
                for (int c = 0; c < 8; ++c) {
                    float hv = fmaxf(bf2f(h0b[(size_t)row * HDIM + c * 16 + col]) + acc[c][r], 0.f);
                    atomicAdd(&pool[g][c * 16 + col], hv);
                }
            }
        } else {
#pragma unroll
            for (int r = 0; r < 4; ++r) {
                int row = rbase + r;
                int g = batch[row];
#pragma unroll
                for (int c = 0; c < 8; ++c) {
                    float hv = fmaxf(bf2f(h0b[(size_t)row * HDIM + c * 16 + col]) + acc[c][r], 0.f);
                    atomicAdd(&gsum[(size_t)g * HDIM + c * 16 + col], hv);
                }
            }
        }
    }

    __syncthreads();
    if (lds_pool) {
        int cc = t & 127;
        for (int s = t >> 7; s < span; s += 2)
            atomicAdd(&gsum[(size_t)(bfirst + s) * HDIM + cc], pool[s][cc]);
    }
}

// ---------------------------------------------------------------- k4a: backbone + value head; writes s2g
__global__ __launch_bounds__(128) void k4a_backbone(const float* __restrict__ gsum,
                                                    const int* __restrict__ cnt,
                                                    const float* __restrict__ W1,
                                                    const float* __restrict__ W2,
                                                    const float* __restrict__ Wv1,
                                                    const float* __restrict__ Wv2,
                                                    float* __restrict__ s2g,
                                                    float* __restrict__ out) {
    int g = blockIdx.x;
    int t = threadIdx.x;
    __shared__ float gv[HDIM];
    __shared__ float s1[HDIM];
    __shared__ float s2v[64];
    __shared__ float v1[32];

    {
        int c = cnt[g];
        gv[t] = (c > 0) ? gsum[(size_t)g * HDIM + t] / (float)c : 0.f;
    }
    __syncthreads();

    {
        float s = 0.f;
#pragma unroll 8
        for (int k = 0; k < HDIM; ++k)
            s = fmaf(gv[k], W1[k * HDIM + t] + W1[(k + HDIM) * HDIM + t], s);
        s1[t] = fmaxf(s, 0.f);
    }
    __syncthreads();

    if (t < 64) {
        float s = 0.f;
#pragma unroll 8
        for (int k = 0; k < HDIM; ++k)
            s = fmaf(s1[k], W2[k * 64 + t], s);
        float sv = fmaxf(s, 0.f);
        s2v[t] = sv;
        s2g[(size_t)g * 64 + t] = sv;
    }
    __syncthreads();

    if (t < 32) {
        float s = 0.f;
#pragma unroll 8
        for (int k = 0; k < 64; ++k)
            s = fmaf(s2v[k], Wv1[k * 32 + t], s);
        v1[t] = fmaxf(s, 0.f);
    }
    __syncthreads();
    if (t == 0) {
        float s = 0.f;
#pragma unroll
        for (int k = 0; k < 32; ++k)
            s = fmaf(v1[k], Wv2[k], s);
        out[1028608 + (size_t)g] = tanhf(s);
    }
}

// ---------------------------------------------------------------- k4b: logits GEMM [512,64]@[64,2009] tiled
__global__ __launch_bounds__(256) void k4b_logits(const float* __restrict__ s2g,
                                                  const float* __restrict__ Wa,
                                                  const float* __restrict__ Ws,
                                                  const float* __restrict__ Wt,
                                                  const float* __restrict__ Wact,
                                                  float* __restrict__ out) {
    int ctile = blockIdx.x & 7;
    int gbase = (blockIdx.x >> 3) * 64;
    int t = threadIdx.x;
    int col = ctile * 256 + t;

    __shared__ float s2s[64][64];   // 16KB
    for (int i = t; i < 4096; i += 256)
        s2s[i >> 6][i & 63] = s2g[(size_t)(gbase + (i >> 6)) * 64 + (i & 63)];

    const float* W = Wa; int colc = 0, ncol = 5; size_t hb = 0;
    bool valid = (col < 2009);
    if (col < 5)        { W = Wa;   colc = col;        ncol = 5;    hb = 0; }
    else if (col < 1005){ W = Ws;   colc = col - 5;    ncol = 1000; hb = 2560; }
    else if (col < 2005){ W = Wt;   colc = col - 1005; ncol = 1000; hb = 514560; }
    else                { W = Wact; colc = col - 2005; ncol = 4;    hb = 1026560; }

    float wr[64];
#pragma unroll 8
    for (int k = 0; k < 64; ++k)
        wr[k] = valid ? W[k * ncol + colc] : 0.f;
    __syncthreads();

    for (int gg = 0; gg < 64; ++gg) {
        float a = 0.f;
#pragma unroll 8
        for (int k = 0; k < 64; ++k)
            a = fmaf(s2s[gg][k], wr[k], a);
        if (valid) out[hb + (size_t)(gbase + gg) * ncol + colc] = a;
    }
}

// ----------------------------------------------------------------
extern "C" void kernel_launch(void* const* d_in, const int* in_sizes, int n_in,
                              void* d_out, int out_size, void* d_ws, size_t ws_size,
                              hipStream_t stream) {
    const float* x     = (const float*)d_in[0];
    const int*   ei    = (const int*)d_in[1];
    const float* ew    = (const float*)d_in[2];
    const int*   batch = (const int*)d_in[4];
    const float* Win   = (const float*)d_in[6];
    const float* Wmsg  = (const float*)d_in[7];
    const float* W1    = (const float*)d_in[8];
    const float* W2    = (const float*)d_in[9];
    const float* Wa    = (const float*)d_in[10];
    const float* Ws    = (const float*)d_in[11];
    const float* Wt    = (const float*)d_in[12];
    const float* Wact  = (const float*)d_in[13];
    const float* Wv1   = (const float*)d_in[14];
    const float* Wv2   = (const float*)d_in[15];
    float* out = (float*)d_out;

    char* p = (char*)d_ws;
    const size_t nb = (size_t)NODES * HDIM * 2;                  // 32 MB
    unsigned short* h0b   = (unsigned short*)p;  p += nb;
    unsigned short* msgb  = (unsigned short*)p;  p += nb;
    float*          gsum  = (float*)p;           p += (size_t)NGRAPH * HDIM * 4;
    float*          s2g   = (float*)p;           p += (size_t)NGRAPH * 64 * 4;
    unsigned short* wfrag = (unsigned short*)p;  p += 32 * 64 * 16;
    int*            count = (int*)p;             p += (size_t)NODES * 4;
    int*            offs  = (int*)p;             p += (size_t)NODES * 4;
    int*            cursor= (int*)p;             p += (size_t)NODES * 4;
    int2*           bucket= (int2*)p;            p += (size_t)EDGES * 8;
    int*            cnt   = (int*)p;             p += (size_t)NGRAPH * 4;
    int*            bsums = (int*)p;             p += 256 * 4;

    hipMemsetAsync(count, 0, (size_t)NODES * 4, stream);

    kprep   <<<12, 256, 0, stream>>>(Wmsg, wfrag, batch, cnt, gsum);
    k1_hist <<<6144, 256, 0, stream>>>(x, Win, h0b, ei, count);
    kh_scanA<<<256, 256, 0, stream>>>(count, offs, bsums);
    kh_scanC<<<256, 256, 0, stream>>>(offs, cursor, bsums);
    kh_fill <<<EDGES / 256, 256, 0, stream>>>(ei, ew, cursor, bucket, EDGES);

    kg_gather<<<(NODES * 64) / 256, 256, 0, stream>>>(h0b, offs, cursor, bucket, msgb, NODES);

    k3a_mfma_pool<<<NODES / 128, 256, 0, stream>>>(msgb, h0b, wfrag, batch, gsum);

    k4a_backbone<<<NGRAPH, 128, 0, stream>>>(gsum, cnt, W1, W2, Wv1, Wv2, s2g, out);
    k4b_logits  <<<64, 256, 0, stream>>>(s2g, Wa, Ws, Wt, Wact, out);
}

// Round 5
// 368.745 us; speedup vs baseline: 1.3354x; 1.3354x over previous
//
#include <hip/hip_runtime.h>
#include <math.h>

#define NODES   131072
#define EDGES   1048576
#define FDIM    32
#define HDIM    128
#define NGRAPH  512

typedef __attribute__((ext_vector_type(8))) short short8v;
typedef __attribute__((ext_vector_type(4))) float float4v;

__device__ __forceinline__ unsigned short f2bf(float f) {
    union { float f; unsigned int u; } v; v.f = f;
    unsigned int u = v.u;
    unsigned int r = (u + 0x7fffu + ((u >> 16) & 1u)) >> 16;   // RNE
    return (unsigned short)r;
}
__device__ __forceinline__ float bf2f(unsigned short u) {
    union { unsigned int u; float f; } v; v.u = ((unsigned int)u) << 16; return v.f;
}

// ---------------------------------------------------------------- k1 | hist fused
__global__ __launch_bounds__(256) void k1_hist(const float* __restrict__ x,
                                               const float* __restrict__ Win,
                                               unsigned short* __restrict__ h0b,
                                               const int* __restrict__ ei,
                                               int* __restrict__ count) {
    int b = blockIdx.x, t = threadIdx.x;
    if (b < 2048) {
        int col = t & (HDIM - 1);
        int group0 = (int)(((size_t)b * 256 + t) >> 7);
        const int stride = 4096;
        for (int n = group0; n < NODES; n += stride) {
            const float* xr = x + (size_t)n * FDIM;
            float s = 0.f;
#pragma unroll
            for (int f = 0; f < FDIM; ++f)
                s = fmaf(xr[f], Win[f * HDIM + col], s);
            h0b[(size_t)n * HDIM + col] = f2bf(s);
        }
    } else {
        int e = (b - 2048) * 256 + t;
        atomicAdd(&count[ei[EDGES + e]], 1);
    }
}

// ---------------------------------------------------------------- scans
__global__ __launch_bounds__(256) void kh_scanA(const int* __restrict__ count,
                                                int* __restrict__ offs,
                                                int* __restrict__ blockSums) {
    int b = blockIdx.x, t = threadIdx.x;
    int base = b * 512 + 2 * t;
    int a0 = count[base], a1 = count[base + 1];
    int pair = a0 + a1;
    __shared__ int sh[256];
    sh[t] = pair;
    __syncthreads();
    for (int off = 1; off < 256; off <<= 1) {
        int v = (t >= off) ? sh[t - off] : 0;
        __syncthreads();
        sh[t] += v;
        __syncthreads();
    }
    int excl = sh[t] - pair;
    offs[base] = excl;
    offs[base + 1] = excl + a0;
    if (t == 255) blockSums[b] = sh[255];
}

__global__ __launch_bounds__(256) void kh_scanC(int* __restrict__ offs,
                                                int* __restrict__ cursor,
                                                const int* __restrict__ bsums) {
    int b = blockIdx.x, t = threadIdx.x;
    __shared__ int sh[256];
    sh[t] = bsums[t];
    __syncthreads();
    for (int off = 1; off < 256; off <<= 1) {
        int v = (t >= off) ? sh[t - off] : 0;
        __syncthreads();
        sh[t] += v;
        __syncthreads();
    }
    int add = (b > 0) ? sh[b - 1] : 0;
    int base = b * 512 + 2 * t;
    int o0 = offs[base] + add, o1 = offs[base + 1] + add;
    offs[base] = o0; offs[base + 1] = o1;
    cursor[base] = o0; cursor[base + 1] = o1;
}

__global__ __launch_bounds__(256) void kh_fill(const int* __restrict__ ei,
                                               const float* __restrict__ ew,
                                               int* __restrict__ cursor,
                                               int2* __restrict__ bucket, int E) {
    int e = blockIdx.x * blockDim.x + threadIdx.x;
    if (e >= E) return;
    int src = ei[e];
    int tgt = ei[E + e];
    float w = ew[e];
    int pos = atomicAdd(&cursor[tgt], 1);
    bucket[pos] = make_int2(src, __float_as_int(w));
}

// ---------------------------------------------------------------- prep: wfrag | cnt | gsum-zero
__global__ __launch_bounds__(256) void kprep(const float* __restrict__ Wmsg,
                                             unsigned short* __restrict__ wfrag,
                                             const int* __restrict__ batch,
                                             int* __restrict__ cnt,
                                             float* __restrict__ gsum) {
    int b = blockIdx.x, t = threadIdx.x;
    if (b < 8) {
        int flat = b * 256 + t;
        int l = flat & 63;
        int fragid = flat >> 6;
        int c = fragid >> 2, kk = fragid & 3;
        int col = c * 16 + (l & 15);
        int k0 = kk * 32 + (l >> 4) * 8;
        short8v v;
#pragma unroll
        for (int j = 0; j < 8; ++j)
            v[j] = (short)f2bf(Wmsg[(k0 + j) * HDIM + col]);
        ((short8v*)wfrag)[flat] = v;
    } else if (b < 10) {
        int g = (b - 8) * 256 + t;
        if (g < NGRAPH) {
            int lo = 0, hi = NODES;
            while (lo < hi) { int m = (lo + hi) >> 1; if (batch[m] < g) lo = m + 1; else hi = m; }
            int start = lo;
            hi = NODES;
            while (lo < hi) { int m = (lo + hi) >> 1; if (batch[m] < g + 1) lo = m + 1; else hi = m; }
            cnt[g] = lo - start;
        }
    } else {
        float4* gz = (float4*)gsum;
        int idx = (b - 10) * 256 + t;
        for (int i = idx; i < 16384; i += 512) gz[i] = make_float4(0.f, 0.f, 0.f, 0.f);
    }
}

// ---------------------------------------------------------------- gather
__global__ __launch_bounds__(256) void kg_gather(const unsigned short* __restrict__ h0b,
                                                 const int* __restrict__ offs,
                                                 const int* __restrict__ cursor,
                                                 const int2* __restrict__ bucket,
                                                 unsigned short* __restrict__ msgb, int N) {
    long long gid = blockIdx.x * (long long)blockDim.x + threadIdx.x;
    int n = (int)(gid >> 6);
    if (n >= N) return;
    int l = (int)(gid & 63);
    int beg = offs[n];
    int end = cursor[n];
    float ax = 0.f, ay = 0.f;
    int j = beg;
    for (; j + 4 <= end; j += 4) {
        int2 e0 = bucket[j], e1 = bucket[j + 1], e2 = bucket[j + 2], e3 = bucket[j + 3];
        unsigned int u0 = ((const unsigned int*)(h0b + (size_t)e0.x * HDIM))[l];
        unsigned int u1 = ((const unsigned int*)(h0b + (size_t)e1.x * HDIM))[l];
        unsigned int u2 = ((const unsigned int*)(h0b + (size_t)e2.x * HDIM))[l];
        unsigned int u3 = ((const unsigned int*)(h0b + (size_t)e3.x * HDIM))[l];
        float w0 = __int_as_float(e0.y), w1 = __int_as_float(e1.y);
        float w2 = __int_as_float(e2.y), w3 = __int_as_float(e3.y);
        ax = fmaf(__uint_as_float(u0 << 16), w0, ax); ay = fmaf(__uint_as_float(u0 & 0xFFFF0000u), w0, ay);
        ax = fmaf(__uint_as_float(u1 << 16), w1, ax); ay = fmaf(__uint_as_float(u1 & 0xFFFF0000u), w1, ay);
        ax = fmaf(__uint_as_float(u2 << 16), w2, ax); ay = fmaf(__uint_as_float(u2 & 0xFFFF0000u), w2, ay);
        ax = fmaf(__uint_as_float(u3 << 16), w3, ax); ay = fmaf(__uint_as_float(u3 & 0xFFFF0000u), w3, ay);
    }
    for (; j < end; ++j) {
        int2 e0 = bucket[j];
        unsigned int u0 = ((const unsigned int*)(h0b + (size_t)e0.x * HDIM))[l];
        float w0 = __int_as_float(e0.y);
        ax = fmaf(__uint_as_float(u0 << 16), w0, ax); ay = fmaf(__uint_as_float(u0 & 0xFFFF0000u), w0, ay);
    }
    ushort2 o; o.x = f2bf(ax); o.y = f2bf(ay);
    ((ushort2*)(msgb + (size_t)n * HDIM))[l] = o;
}

// ---------------------------------------------------------------- k3a: MFMA GEMM + relu + fused pool
__global__ __launch_bounds__(256) void k3a_mfma_pool(const unsigned short* __restrict__ msgb,
                                                     const unsigned short* __restrict__ h0b,
                                                     const unsigned short* __restrict__ wfrag,
                                                     const int* __restrict__ batch,
                                                     float* __restrict__ gsum) {
    __shared__ __align__(16) unsigned short blds[32 * 64 * 8];
    __shared__ float pool[8][HDIM];

    int t = threadIdx.x;
    int wid = t >> 6, l = t & 63;
    int base = blockIdx.x * 128;

    {
        const uint4* s = (const uint4*)wfrag;
        uint4* d = (uint4*)blds;
#pragma unroll
        for (int i = 0; i < 8; ++i) d[t + 256 * i] = s[t + 256 * i];
    }

    int bfirst = batch[base];
    int blast  = batch[base + 127];
    int span = blast - bfirst + 1;
    bool lds_pool = (span <= 8);
    if (lds_pool) {
        float* pf = (float*)pool;
        for (int i = t; i < 8 * HDIM; i += 256) pf[i] = 0.f;
    }
    __syncthreads();

    const short8v* Bl = (const short8v*)blds;
    int col = l & 15;
    int rsub = (l >> 4) * 4;

#pragma unroll
    for (int s = 0; s < 2; ++s) {
        int strip = base + wid * 32 + s * 16;
        const short8v* mrow = (const short8v*)(msgb + (size_t)(strip + col) * HDIM);
        short8v af[4];
#pragma unroll
        for (int kk = 0; kk < 4; ++kk)
            af[kk] = mrow[kk * 4 + (l >> 4)];

        float4v acc[8];
#pragma unroll
        for (int c = 0; c < 8; ++c) acc[c] = (float4v){0.f, 0.f, 0.f, 0.f};
#pragma unroll
        for (int kk = 0; kk < 4; ++kk)
#pragma unroll
            for (int c = 0; c < 8; ++c)
                acc[c] = __builtin_amdgcn_mfma_f32_16x16x32_bf16(af[kk], Bl[(c * 4 + kk) * 64 + l], acc[c], 0, 0, 0);

        int rbase = strip + rsub;
        if (lds_pool) {
#pragma unroll
            for (int r = 0; r < 4; ++r) {
                int row = rbase + r;
                int g = batch[row] - bfirst;
#pragma unroll
                for (int c = 0; c < 8; ++c) {
                    float hv = fmaxf(bf2f(h0b[(size_t)row * HDIM + c * 16 + col]) + acc[c][r], 0.f);
                    atomicAdd(&pool[g][c * 16 + col], hv);
                }
            }
        } else {
#pragma unroll
            for (int r = 0; r < 4; ++r) {
                int row = rbase + r;
                int g = batch[row];
#pragma unroll
                for (int c = 0; c < 8; ++c) {
                    float hv = fmaxf(bf2f(h0b[(size_t)row * HDIM + c * 16 + col]) + acc[c][r], 0.f);
                    atomicAdd(&gsum[(size_t)g * HDIM + c * 16 + col], hv);
                }
            }
        }
    }

    __syncthreads();
    if (lds_pool) {
        int cc = t & 127;
        for (int s = t >> 7; s < span; s += 2)
            atomicAdd(&gsum[(size_t)(bfirst + s) * HDIM + cc], pool[s][cc]);
    }
}

// ---------------------------------------------------------------- k4a: backbone + value head; writes s2g
__global__ __launch_bounds__(128) void k4a_backbone(const float* __restrict__ gsum,
                                                    const int* __restrict__ cnt,
                                                    const float* __restrict__ W1,
                                                    const float* __restrict__ W2,
                                                    const float* __restrict__ Wv1,
                                                    const float* __restrict__ Wv2,
                                                    float* __restrict__ s2g,
                                                    float* __restrict__ out) {
    int g = blockIdx.x;
    int t = threadIdx.x;
    __shared__ float gv[HDIM];
    __shared__ float s1[HDIM];
    __shared__ float s2v[64];
    __shared__ float v1[32];

    {
        int c = cnt[g];
        gv[t] = (c > 0) ? gsum[(size_t)g * HDIM + t] / (float)c : 0.f;
    }
    __syncthreads();

    {
        float s = 0.f;
#pragma unroll 8
        for (int k = 0; k < HDIM; ++k)
            s = fmaf(gv[k], W1[k * HDIM + t] + W1[(k + HDIM) * HDIM + t], s);
        s1[t] = fmaxf(s, 0.f);
    }
    __syncthreads();

    if (t < 64) {
        float s = 0.f;
#pragma unroll 8
        for (int k = 0; k < HDIM; ++k)
            s = fmaf(s1[k], W2[k * 64 + t], s);
        float sv = fmaxf(s, 0.f);
        s2v[t] = sv;
        s2g[(size_t)g * 64 + t] = sv;
    }
    __syncthreads();

    if (t < 32) {
        float s = 0.f;
#pragma unroll 8
        for (int k = 0; k < 64; ++k)
            s = fmaf(s2v[k], Wv1[k * 32 + t], s);
        v1[t] = fmaxf(s, 0.f);
    }
    __syncthreads();
    if (t == 0) {
        float s = 0.f;
#pragma unroll
        for (int k = 0; k < 32; ++k)
            s = fmaf(v1[k], Wv2[k], s);
        out[1028608 + (size_t)g] = tanhf(s);
    }
}

// ---------------------------------------------------------------- k4b: logits GEMM [512,64]@[64,2009]
// 256 blocks = 8 col-tiles(256) x 32 graph-tiles(16). Thread = one column.
// W column fully unrolled into 64 VGPRs (static indices -> registers, rule #20).
__global__ __launch_bounds__(256) void k4b_logits(const float* __restrict__ s2g,
                                                  const float* __restrict__ Wa,
                                                  const float* __restrict__ Ws,
                                                  const float* __restrict__ Wt,
                                                  const float* __restrict__ Wact,
                                                  float* __restrict__ out) {
    int ctile = blockIdx.x & 7;
    int gbase = (blockIdx.x >> 3) * 16;
    int t = threadIdx.x;
    int col = ctile * 256 + t;

    __shared__ float4 s2s4[16][16];     // 16 graphs x 64 floats = 4KB
    {
        int g = t >> 4, q = t & 15;
        s2s4[g][q] = ((const float4*)(s2g + (size_t)(gbase + g) * 64))[q];
    }

    bool valid = (col < 2009);
    const float* W = Wa; int colc = 0, ncol = 5; size_t hb = 0;
    if (col < 5)        { W = Wa;   colc = col;        ncol = 5;    hb = 0; }
    else if (col < 1005){ W = Ws;   colc = col - 5;    ncol = 1000; hb = 2560; }
    else if (col < 2005){ W = Wt;   colc = col - 1005; ncol = 1000; hb = 514560; }
    else                { W = Wact; colc = col - 2005; ncol = 4;    hb = 1026560; }

    float wr[64];
#pragma unroll
    for (int k = 0; k < 64; ++k)               // full unroll: static indices -> VGPRs
        wr[k] = valid ? W[(size_t)k * ncol + colc] : 0.f;
    __syncthreads();

    for (int gg = 0; gg < 16; ++gg) {
        const float4* s4 = (const float4*)s2s4[gg];
        float a = 0.f;
#pragma unroll
        for (int q = 0; q < 16; ++q) {
            float4 v = s4[q];
            a = fmaf(v.x, wr[4 * q + 0], a);
            a = fmaf(v.y, wr[4 * q + 1], a);
            a = fmaf(v.z, wr[4 * q + 2], a);
            a = fmaf(v.w, wr[4 * q + 3], a);
        }
        if (valid) out[hb + (size_t)(gbase + gg) * ncol + colc] = a;
    }
}

// ----------------------------------------------------------------
extern "C" void kernel_launch(void* const* d_in, const int* in_sizes, int n_in,
                              void* d_out, int out_size, void* d_ws, size_t ws_size,
                              hipStream_t stream) {
    const float* x     = (const float*)d_in[0];
    const int*   ei    = (const int*)d_in[1];
    const float* ew    = (const float*)d_in[2];
    const int*   batch = (const int*)d_in[4];
    const float* Win   = (const float*)d_in[6];
    const float* Wmsg  = (const float*)d_in[7];
    const float* W1    = (const float*)d_in[8];
    const float* W2    = (const float*)d_in[9];
    const float* Wa    = (const float*)d_in[10];
    const float* Ws    = (const float*)d_in[11];
    const float* Wt    = (const float*)d_in[12];
    const float* Wact  = (const float*)d_in[13];
    const float* Wv1   = (const float*)d_in[14];
    const float* Wv2   = (const float*)d_in[15];
    float* out = (float*)d_out;

    char* p = (char*)d_ws;
    const size_t nb = (size_t)NODES * HDIM * 2;
    unsigned short* h0b   = (unsigned short*)p;  p += nb;
    unsigned short* msgb  = (unsigned short*)p;  p += nb;
    float*          gsum  = (float*)p;           p += (size_t)NGRAPH * HDIM * 4;
    float*          s2g   = (float*)p;           p += (size_t)NGRAPH * 64 * 4;
    unsigned short* wfrag = (unsigned short*)p;  p += 32 * 64 * 16;
    int*            count = (int*)p;             p += (size_t)NODES * 4;
    int*            offs  = (int*)p;             p += (size_t)NODES * 4;
    int*            cursor= (int*)p;             p += (size_t)NODES * 4;
    int2*           bucket= (int2*)p;            p += (size_t)EDGES * 8;
    int*            cnt   = (int*)p;             p += (size_t)NGRAPH * 4;
    int*            bsums = (int*)p;             p += 256 * 4;

    hipMemsetAsync(count, 0, (size_t)NODES * 4, stream);

    kprep   <<<12, 256, 0, stream>>>(Wmsg, wfrag, batch, cnt, gsum);
    k1_hist <<<6144, 256, 0, stream>>>(x, Win, h0b, ei, count);
    kh_scanA<<<256, 256, 0, stream>>>(count, offs, bsums);
    kh_scanC<<<256, 256, 0, stream>>>(offs, cursor, bsums);
    kh_fill <<<EDGES / 256, 256, 0, stream>>>(ei, ew, cursor, bucket, EDGES);

    kg_gather<<<(NODES * 64) / 256, 256, 0, stream>>>(h0b, offs, cursor, bucket, msgb, NODES);

    k3a_mfma_pool<<<NODES / 128, 256, 0, stream>>>(msgb, h0b, wfrag, batch, gsum);

    k4a_backbone<<<NGRAPH, 128, 0, stream>>>(gsum, cnt, W1, W2, Wv1, Wv2, s2g, out);
    k4b_logits  <<<256, 256, 0, stream>>>(s2g, Wa, Ws, Wt, Wact, out);
}

// Round 6
// 313.491 us; speedup vs baseline: 1.5708x; 1.1763x over previous
//
#include <hip/hip_runtime.h>
#include <math.h>

#define NODES   131072
#define EDGES   1048576
#define FDIM    32
#define HDIM    128
#define NGRAPH  512

typedef __attribute__((ext_vector_type(8))) short short8v;
typedef __attribute__((ext_vector_type(4))) float float4v;

__device__ __forceinline__ unsigned short f2bf(float f) {
    union { float f; unsigned int u; } v; v.f = f;
    unsigned int u = v.u;
    unsigned int r = (u + 0x7fffu + ((u >> 16) & 1u)) >> 16;   // RNE
    return (unsigned short)r;
}
__device__ __forceinline__ float bf2f(unsigned short u) {
    union { unsigned int u; float f; } v; v.u = ((unsigned int)u) << 16; return v.f;
}

// ---------------------------------------------------------------- k1: MFMA projection | hist fused
// blocks [0,1024): h0b = bf16(X @ W_in) via 16x16x32 MFMA (X read once, coalesced)
// blocks [1024,5120): degree histogram
__global__ __launch_bounds__(256) void k1_mfma(const float* __restrict__ x,
                                               const unsigned short* __restrict__ winfrag,
                                               unsigned short* __restrict__ h0b,
                                               const int* __restrict__ ei,
                                               int* __restrict__ count) {
    int b = blockIdx.x, t = threadIdx.x;
    if (b < 1024) {
        int wid = t >> 6, l = t & 63;
        int base = b * 128;

        // B fragments: Win in frag order, 8 frags x 16B/lane = 32 VGPRs
        const short8v* wf8 = (const short8v*)winfrag;
        short8v wfr[8];
#pragma unroll
        for (int c = 0; c < 8; ++c) wfr[c] = wf8[c * 64 + l];

#pragma unroll
        for (int s = 0; s < 2; ++s) {
            int strip = base + wid * 32 + s * 16;
            int row = strip + (l & 15);
            const float* xr = x + (size_t)row * FDIM + (l >> 4) * 8;
            float4 x0 = ((const float4*)xr)[0];
            float4 x1 = ((const float4*)xr)[1];
            short8v af;
            af[0] = (short)f2bf(x0.x); af[1] = (short)f2bf(x0.y);
            af[2] = (short)f2bf(x0.z); af[3] = (short)f2bf(x0.w);
            af[4] = (short)f2bf(x1.x); af[5] = (short)f2bf(x1.y);
            af[6] = (short)f2bf(x1.z); af[7] = (short)f2bf(x1.w);

            float4v acc[8];
#pragma unroll
            for (int c = 0; c < 8; ++c) acc[c] = (float4v){0.f, 0.f, 0.f, 0.f};
#pragma unroll
            for (int c = 0; c < 8; ++c)
                acc[c] = __builtin_amdgcn_mfma_f32_16x16x32_bf16(af, wfr[c], acc[c], 0, 0, 0);

            int rbase = strip + (l >> 4) * 4;   // C/D: col = lane&15, row = (lane>>4)*4 + reg
            int col = l & 15;
#pragma unroll
            for (int r = 0; r < 4; ++r)
#pragma unroll
                for (int c = 0; c < 8; ++c)
                    h0b[(size_t)(rbase + r) * HDIM + c * 16 + col] = f2bf(acc[c][r]);
        }
    } else {
        int e = (b - 1024) * 256 + t;
        atomicAdd(&count[ei[EDGES + e]], 1);
    }
}

// ---------------------------------------------------------------- scans
__global__ __launch_bounds__(256) void kh_scanA(const int* __restrict__ count,
                                                int* __restrict__ offs,
                                                int* __restrict__ blockSums) {
    int b = blockIdx.x, t = threadIdx.x;
    int base = b * 512 + 2 * t;
    int a0 = count[base], a1 = count[base + 1];
    int pair = a0 + a1;
    __shared__ int sh[256];
    sh[t] = pair;
    __syncthreads();
    for (int off = 1; off < 256; off <<= 1) {
        int v = (t >= off) ? sh[t - off] : 0;
        __syncthreads();
        sh[t] += v;
        __syncthreads();
    }
    int excl = sh[t] - pair;
    offs[base] = excl;
    offs[base + 1] = excl + a0;
    if (t == 255) blockSums[b] = sh[255];
}

__global__ __launch_bounds__(256) void kh_scanC(int* __restrict__ offs,
                                                int* __restrict__ cursor,
                                                const int* __restrict__ bsums) {
    int b = blockIdx.x, t = threadIdx.x;
    __shared__ int sh[256];
    sh[t] = bsums[t];
    __syncthreads();
    for (int off = 1; off < 256; off <<= 1) {
        int v = (t >= off) ? sh[t - off] : 0;
        __syncthreads();
        sh[t] += v;
        __syncthreads();
    }
    int add = (b > 0) ? sh[b - 1] : 0;
    int base = b * 512 + 2 * t;
    int o0 = offs[base] + add, o1 = offs[base + 1] + add;
    offs[base] = o0; offs[base + 1] = o1;
    cursor[base] = o0; cursor[base + 1] = o1;
}

__global__ __launch_bounds__(256) void kh_fill(const int* __restrict__ ei,
                                               const float* __restrict__ ew,
                                               int* __restrict__ cursor,
                                               int2* __restrict__ bucket, int E) {
    int e = blockIdx.x * blockDim.x + threadIdx.x;
    if (e >= E) return;
    int src = ei[e];
    int tgt = ei[E + e];
    float w = ew[e];
    int pos = atomicAdd(&cursor[tgt], 1);
    bucket[pos] = make_int2(src, __float_as_int(w));
}

// ---------------------------------------------------------------- prep: wfrag | winfrag | cnt | gsum-zero
__global__ __launch_bounds__(256) void kprep(const float* __restrict__ Wmsg,
                                             const float* __restrict__ Win,
                                             unsigned short* __restrict__ wfrag,
                                             unsigned short* __restrict__ winfrag,
                                             const int* __restrict__ batch,
                                             int* __restrict__ cnt,
                                             float* __restrict__ gsum) {
    int b = blockIdx.x, t = threadIdx.x;
    if (b < 8) {
        int flat = b * 256 + t;
        int l = flat & 63;
        int fragid = flat >> 6;
        int c = fragid >> 2, kk = fragid & 3;
        int col = c * 16 + (l & 15);
        int k0 = kk * 32 + (l >> 4) * 8;
        short8v v;
#pragma unroll
        for (int j = 0; j < 8; ++j)
            v[j] = (short)f2bf(Wmsg[(k0 + j) * HDIM + col]);
        ((short8v*)wfrag)[flat] = v;
    } else if (b < 10) {
        int flat = (b - 8) * 256 + t;          // 0..511
        int l = flat & 63;
        int c = flat >> 6;                     // 0..7
        int col = c * 16 + (l & 15);
        int k0 = (l >> 4) * 8;
        short8v v;
#pragma unroll
        for (int j = 0; j < 8; ++j)
            v[j] = (short)f2bf(Win[(k0 + j) * HDIM + col]);
        ((short8v*)winfrag)[flat] = v;
    } else if (b < 12) {
        int g = (b - 10) * 256 + t;
        if (g < NGRAPH) {
            int lo = 0, hi = NODES;
            while (lo < hi) { int m = (lo + hi) >> 1; if (batch[m] < g) lo = m + 1; else hi = m; }
            int start = lo;
            hi = NODES;
            while (lo < hi) { int m = (lo + hi) >> 1; if (batch[m] < g + 1) lo = m + 1; else hi = m; }
            cnt[g] = lo - start;
        }
    } else {
        float4* gz = (float4*)gsum;
        int idx = (b - 12) * 256 + t;
        for (int i = idx; i < 16384; i += 512) gz[i] = make_float4(0.f, 0.f, 0.f, 0.f);
    }
}

// ---------------------------------------------------------------- gather
__global__ __launch_bounds__(256) void kg_gather(const unsigned short* __restrict__ h0b,
                                                 const int* __restrict__ offs,
                                                 const int* __restrict__ cursor,
                                                 const int2* __restrict__ bucket,
                                                 unsigned short* __restrict__ msgb, int N) {
    long long gid = blockIdx.x * (long long)blockDim.x + threadIdx.x;
    int n = (int)(gid >> 6);
    if (n >= N) return;
    int l = (int)(gid & 63);
    int beg = offs[n];
    int end = cursor[n];
    float ax = 0.f, ay = 0.f;
    int j = beg;
    for (; j + 4 <= end; j += 4) {
        int2 e0 = bucket[j], e1 = bucket[j + 1], e2 = bucket[j + 2], e3 = bucket[j + 3];
        unsigned int u0 = ((const unsigned int*)(h0b + (size_t)e0.x * HDIM))[l];
        unsigned int u1 = ((const unsigned int*)(h0b + (size_t)e1.x * HDIM))[l];
        unsigned int u2 = ((const unsigned int*)(h0b + (size_t)e2.x * HDIM))[l];
        unsigned int u3 = ((const unsigned int*)(h0b + (size_t)e3.x * HDIM))[l];
        float w0 = __int_as_float(e0.y), w1 = __int_as_float(e1.y);
        float w2 = __int_as_float(e2.y), w3 = __int_as_float(e3.y);
        ax = fmaf(__uint_as_float(u0 << 16), w0, ax); ay = fmaf(__uint_as_float(u0 & 0xFFFF0000u), w0, ay);
        ax = fmaf(__uint_as_float(u1 << 16), w1, ax); ay = fmaf(__uint_as_float(u1 & 0xFFFF0000u), w1, ay);
        ax = fmaf(__uint_as_float(u2 << 16), w2, ax); ay = fmaf(__uint_as_float(u2 & 0xFFFF0000u), w2, ay);
        ax = fmaf(__uint_as_float(u3 << 16), w3, ax); ay = fmaf(__uint_as_float(u3 & 0xFFFF0000u), w3, ay);
    }
    for (; j < end; ++j) {
        int2 e0 = bucket[j];
        unsigned int u0 = ((const unsigned int*)(h0b + (size_t)e0.x * HDIM))[l];
        float w0 = __int_as_float(e0.y);
        ax = fmaf(__uint_as_float(u0 << 16), w0, ax); ay = fmaf(__uint_as_float(u0 & 0xFFFF0000u), w0, ay);
    }
    ushort2 o; o.x = f2bf(ax); o.y = f2bf(ay);
    ((ushort2*)(msgb + (size_t)n * HDIM))[l] = o;
}

// ---------------------------------------------------------------- k3a: MFMA GEMM + relu + fused pool
__global__ __launch_bounds__(256) void k3a_mfma_pool(const unsigned short* __restrict__ msgb,
                                                     const unsigned short* __restrict__ h0b,
                                                     const unsigned short* __restrict__ wfrag,
                                                     const int* __restrict__ batch,
                                                     float* __restrict__ gsum) {
    __shared__ __align__(16) unsigned short blds[32 * 64 * 8];
    __shared__ float pool[8][HDIM];

    int t = threadIdx.x;
    int wid = t >> 6, l = t & 63;
    int base = blockIdx.x * 128;

    {
        const uint4* s = (const uint4*)wfrag;
        uint4* d = (uint4*)blds;
#pragma unroll
        for (int i = 0; i < 8; ++i) d[t + 256 * i] = s[t + 256 * i];
    }

    int bfirst = batch[base];
    int blast  = batch[base + 127];
    int span = blast - bfirst + 1;
    bool lds_pool = (span <= 8);
    if (lds_pool) {
        float* pf = (float*)pool;
        for (int i = t; i < 8 * HDIM; i += 256) pf[i] = 0.f;
    }
    __syncthreads();

    const short8v* Bl = (const short8v*)blds;
    int col = l & 15;
    int rsub = (l >> 4) * 4;

#pragma unroll
    for (int s = 0; s < 2; ++s) {
        int strip = base + wid * 32 + s * 16;
        const short8v* mrow = (const short8v*)(msgb + (size_t)(strip + col) * HDIM);
        short8v af[4];
#pragma unroll
        for (int kk = 0; kk < 4; ++kk)
            af[kk] = mrow[kk * 4 + (l >> 4)];

        float4v acc[8];
#pragma unroll
        for (int c = 0; c < 8; ++c) acc[c] = (float4v){0.f, 0.f, 0.f, 0.f};
#pragma unroll
        for (int kk = 0; kk < 4; ++kk)
#pragma unroll
            for (int c = 0; c < 8; ++c)
                acc[c] = __builtin_amdgcn_mfma_f32_16x16x32_bf16(af[kk], Bl[(c * 4 + kk) * 64 + l], acc[c], 0, 0, 0);

        int rbase = strip + rsub;
        if (lds_pool) {
#pragma unroll
            for (int r = 0; r < 4; ++r) {
                int row = rbase + r;
                int g = batch[row] - bfirst;
#pragma unroll
                for (int c = 0; c < 8; ++c) {
                    float hv = fmaxf(bf2f(h0b[(size_t)row * HDIM + c * 16 + col]) + acc[c][r], 0.f);
                    atomicAdd(&pool[g][c * 16 + col], hv);
                }
            }
        } else {
#pragma unroll
            for (int r = 0; r < 4; ++r) {
                int row = rbase + r;
                int g = batch[row];
#pragma unroll
                for (int c = 0; c < 8; ++c) {
                    float hv = fmaxf(bf2f(h0b[(size_t)row * HDIM + c * 16 + col]) + acc[c][r], 0.f);
                    atomicAdd(&gsum[(size_t)g * HDIM + c * 16 + col], hv);
                }
            }
        }
    }

    __syncthreads();
    if (lds_pool) {
        int cc = t & 127;
        for (int s = t >> 7; s < span; s += 2)
            atomicAdd(&gsum[(size_t)(bfirst + s) * HDIM + cc], pool[s][cc]);
    }
}

// ---------------------------------------------------------------- k4a: backbone + value head; writes s2g
__global__ __launch_bounds__(128) void k4a_backbone(const float* __restrict__ gsum,
                                                    const int* __restrict__ cnt,
                                                    const float* __restrict__ W1,
                                                    const float* __restrict__ W2,
                                                    const float* __restrict__ Wv1,
                                                    const float* __restrict__ Wv2,
                                                    float* __restrict__ s2g,
                                                    float* __restrict__ out) {
    int g = blockIdx.x;
    int t = threadIdx.x;
    __shared__ float gv[HDIM];
    __shared__ float s1[HDIM];
    __shared__ float s2v[64];
    __shared__ float v1[32];

    {
        int c = cnt[g];
        gv[t] = (c > 0) ? gsum[(size_t)g * HDIM + t] / (float)c : 0.f;
    }
    __syncthreads();

    {
        float s = 0.f;
#pragma unroll 8
        for (int k = 0; k < HDIM; ++k)
            s = fmaf(gv[k], W1[k * HDIM + t] + W1[(k + HDIM) * HDIM + t], s);
        s1[t] = fmaxf(s, 0.f);
    }
    __syncthreads();

    if (t < 64) {
        float s = 0.f;
#pragma unroll 8
        for (int k = 0; k < HDIM; ++k)
            s = fmaf(s1[k], W2[k * 64 + t], s);
        float sv = fmaxf(s, 0.f);
        s2v[t] = sv;
        s2g[(size_t)g * 64 + t] = sv;
    }
    __syncthreads();

    if (t < 32) {
        float s = 0.f;
#pragma unroll 8
        for (int k = 0; k < 64; ++k)
            s = fmaf(s2v[k], Wv1[k * 32 + t], s);
        v1[t] = fmaxf(s, 0.f);
    }
    __syncthreads();
    if (t == 0) {
        float s = 0.f;
#pragma unroll
        for (int k = 0; k < 32; ++k)
            s = fmaf(v1[k], Wv2[k], s);
        out[1028608 + (size_t)g] = tanhf(s);
    }
}

// ---------------------------------------------------------------- k4b: logits GEMM [512,64]@[64,2009]
__global__ __launch_bounds__(256) void k4b_logits(const float* __restrict__ s2g,
                                                  const float* __restrict__ Wa,
                                                  const float* __restrict__ Ws,
                                                  const float* __restrict__ Wt,
                                                  const float* __restrict__ Wact,
                                                  float* __restrict__ out) {
    int ctile = blockIdx.x & 7;
    int gbase = (blockIdx.x >> 3) * 16;
    int t = threadIdx.x;
    int col = ctile * 256 + t;

    __shared__ float4 s2s4[16][16];
    {
        int g = t >> 4, q = t & 15;
        s2s4[g][q] = ((const float4*)(s2g + (size_t)(gbase + g) * 64))[q];
    }

    bool valid = (col < 2009);
    const float* W = Wa; int colc = 0, ncol = 5; size_t hb = 0;
    if (col < 5)        { W = Wa;   colc = col;        ncol = 5;    hb = 0; }
    else if (col < 1005){ W = Ws;   colc = col - 5;    ncol = 1000; hb = 2560; }
    else if (col < 2005){ W = Wt;   colc = col - 1005; ncol = 1000; hb = 514560; }
    else                { W = Wact; colc = col - 2005; ncol = 4;    hb = 1026560; }

    float wr[64];
#pragma unroll
    for (int k = 0; k < 64; ++k)
        wr[k] = valid ? W[(size_t)k * ncol + colc] : 0.f;
    __syncthreads();

    for (int gg = 0; gg < 16; ++gg) {
        const float4* s4 = (const float4*)s2s4[gg];
        float a = 0.f;
#pragma unroll
        for (int q = 0; q < 16; ++q) {
            float4 v = s4[q];
            a = fmaf(v.x, wr[4 * q + 0], a);
            a = fmaf(v.y, wr[4 * q + 1], a);
            a = fmaf(v.z, wr[4 * q + 2], a);
            a = fmaf(v.w, wr[4 * q + 3], a);
        }
        if (valid) out[hb + (size_t)(gbase + gg) * ncol + colc] = a;
    }
}

// ----------------------------------------------------------------
extern "C" void kernel_launch(void* const* d_in, const int* in_sizes, int n_in,
                              void* d_out, int out_size, void* d_ws, size_t ws_size,
                              hipStream_t stream) {
    const float* x     = (const float*)d_in[0];
    const int*   ei    = (const int*)d_in[1];
    const float* ew    = (const float*)d_in[2];
    const int*   batch = (const int*)d_in[4];
    const float* Win   = (const float*)d_in[6];
    const float* Wmsg  = (const float*)d_in[7];
    const float* W1    = (const float*)d_in[8];
    const float* W2    = (const float*)d_in[9];
    const float* Wa    = (const float*)d_in[10];
    const float* Ws    = (const float*)d_in[11];
    const float* Wt    = (const float*)d_in[12];
    const float* Wact  = (const float*)d_in[13];
    const float* Wv1   = (const float*)d_in[14];
    const float* Wv2   = (const float*)d_in[15];
    float* out = (float*)d_out;

    char* p = (char*)d_ws;
    const size_t nb = (size_t)NODES * HDIM * 2;
    unsigned short* h0b    = (unsigned short*)p;  p += nb;
    unsigned short* msgb   = (unsigned short*)p;  p += nb;
    float*          gsum   = (float*)p;           p += (size_t)NGRAPH * HDIM * 4;
    float*          s2g    = (float*)p;           p += (size_t)NGRAPH * 64 * 4;
    unsigned short* wfrag  = (unsigned short*)p;  p += 32 * 64 * 16;
    unsigned short* winfrag= (unsigned short*)p;  p += 8 * 64 * 16;
    int*            count  = (int*)p;             p += (size_t)NODES * 4;
    int*            offs   = (int*)p;             p += (size_t)NODES * 4;
    int*            cursor = (int*)p;             p += (size_t)NODES * 4;
    int2*           bucket = (int2*)p;            p += (size_t)EDGES * 8;
    int*            cnt    = (int*)p;             p += (size_t)NGRAPH * 4;
    int*            bsums  = (int*)p;             p += 256 * 4;

    hipMemsetAsync(count, 0, (size_t)NODES * 4, stream);

    kprep   <<<14, 256, 0, stream>>>(Wmsg, Win, wfrag, winfrag, batch, cnt, gsum);
    k1_mfma <<<5120, 256, 0, stream>>>(x, winfrag, h0b, ei, count);
    kh_scanA<<<256, 256, 0, stream>>>(count, offs, bsums);
    kh_scanC<<<256, 256, 0, stream>>>(offs, cursor, bsums);
    kh_fill <<<EDGES / 256, 256, 0, stream>>>(ei, ew, cursor, bucket, EDGES);

    kg_gather<<<(NODES * 64) / 256, 256, 0, stream>>>(h0b, offs, cursor, bucket, msgb, NODES);

    k3a_mfma_pool<<<NODES / 128, 256, 0, stream>>>(msgb, h0b, wfrag, batch, gsum);

    k4a_backbone<<<NGRAPH, 128, 0, stream>>>(gsum, cnt, W1, W2, Wv1, Wv2, s2g, out);
    k4b_logits  <<<256, 256, 0, stream>>>(s2g, Wa, Ws, Wt, Wact, out);
}